// Round 10
// baseline (287.449 us; speedup 1.0000x reference)
//
#include <hip/hip_runtime.h>

#define NN 20000
#define IN_DIM 256
#define HID 128
#define OUT_DIM 64
#define N_LAYERS 4
#define N_PATHS 8
#define PATH_LEN 8
#define N_TYPES 2

typedef __attribute__((ext_vector_type(8))) short bf16x8;
typedef __attribute__((ext_vector_type(4))) float f32x4;

__device__ __forceinline__ float bf2f(ushort u) {
    union { uint u; float f; } c; c.u = ((uint)u) << 16; return c.f;
}
__device__ __forceinline__ ushort f2bf(float f) {
    union { float f; uint u; } c; c.f = f;
    uint u = c.u;
    uint lsb = (u >> 16) & 1;
    u += 0x7fffu + lsb;          // round-to-nearest-even (inputs finite)
    return (ushort)(u >> 16);
}

// ---------------------------------------------------------------------------
// One-shot fp32 -> bf16 conversion of all weight matrices (quad-per-thread).
// ---------------------------------------------------------------------------
__global__ __launch_bounds__(256) void cvt_weights(
    const float* __restrict__ w_in, const float* __restrict__ w_layer,
    const float* __restrict__ w_out,
    ushort* __restrict__ o_in, ushort* __restrict__ o_layer,
    ushort* __restrict__ o_out)
{
    int i = blockIdx.x * 256 + threadIdx.x;
    const float* s; ushort* d; int off;
    if (i < 8192)        { s = w_in;    d = o_in;    off = i; }
    else if (i < 40960)  { s = w_layer; d = o_layer; off = i - 8192; }
    else if (i < 43008)  { s = w_out;   d = o_out;   off = i - 40960; }
    else return;
    float4 v = ((const float4*)s)[off];
    ushort4 o;
    o.x = f2bf(v.x); o.y = f2bf(v.y); o.z = f2bf(v.z); o.w = f2bf(v.w);
    ((ushort4*)d)[off] = o;
}

// ---------------------------------------------------------------------------
// bf16 MFMA GEMM: C = epilogue(A[M,K] @ W[N,K]^T), fp32 accumulate.
// BM=32 (grid 625 on 256 CUs -> no 313-block quantization stall).
// 4 waves: wr = w>>1 (16-row blocks), wc = w&1 (N/2-col halves).
// LDS XOR-swizzle on 16B granules: elem ^= (row&7)<<3 (T2, conflict-free).
// AF32: A operand is fp32 in global, converted to bf16 while staging.
// EPI 0: bf16 out = relu(acc + bias[n])
// EPI 1: bf16 out = 0.8*relu(acc) + 0.1*pre + 0.1*in0
// EPI 2: f32  out = relu(acc + bias[n])
// M must be a multiple of 32 (20000 = 625*32).
// ---------------------------------------------------------------------------
template <int N, int K, int EPI, bool AF32>
__global__ __launch_bounds__(256) void gemm_mfma(
    const void* __restrict__ Ap,
    const ushort* __restrict__ W,     // [N][K] bf16
    const float* __restrict__ bias,
    const ushort* __restrict__ pre,
    const ushort* __restrict__ in0,
    void* __restrict__ Cout,
    int M)
{
    constexpr int BM = 32, BK = 64;
    constexpr int NC = N / 32;              // col-frags per wave (4 or 2)

    __shared__ short As[BM * BK];           // 4 KB
    __shared__ short Ws[N * BK];            // 16 KB (N=128) / 8 KB (N=64)

    const int tid = threadIdx.x;
    const int lane = tid & 63;
    const int w = tid >> 6;
    const int wr = w >> 1, wc = w & 1;
    const int m0 = blockIdx.x * BM;
    const int l15 = lane & 15, l4 = lane >> 4;

    f32x4 acc[NC];
#pragma unroll
    for (int nc = 0; nc < NC; ++nc)
#pragma unroll
        for (int j = 0; j < 4; ++j) acc[nc][j] = 0.f;

    for (int k0 = 0; k0 < K; k0 += BK) {
        // ---- stage A tile: 256 granules, exactly 1 per thread ----
        {
            int r = tid >> 3, kc = tid & 7;
            int gr = m0 + r;
            bf16x8 v;
            if constexpr (AF32) {
                const float* Af = (const float*)Ap;
                float4 v0 = *(const float4*)(Af + (long)gr * K + k0 + kc * 8);
                float4 v1 = *(const float4*)(Af + (long)gr * K + k0 + kc * 8 + 4);
                v[0] = (short)f2bf(v0.x); v[1] = (short)f2bf(v0.y);
                v[2] = (short)f2bf(v0.z); v[3] = (short)f2bf(v0.w);
                v[4] = (short)f2bf(v1.x); v[5] = (short)f2bf(v1.y);
                v[6] = (short)f2bf(v1.z); v[7] = (short)f2bf(v1.w);
            } else {
                v = *(const bf16x8*)((const ushort*)Ap + (long)gr * K + k0 + kc * 8);
            }
            int di = (tid * 8) ^ ((r & 7) << 3);
            *(bf16x8*)&As[di] = v;
        }
        // ---- stage W tile (bf16) ----
#pragma unroll
        for (int c = tid; c < N * 8; c += 256) {
            int r = c >> 3, kc = c & 7;
            bf16x8 v = *(const bf16x8*)(W + (long)r * K + k0 + kc * 8);
            int di = (r * BK + kc * 8) ^ ((r & 7) << 3);
            *(bf16x8*)&Ws[di] = v;
        }
        __syncthreads();

#pragma unroll
        for (int ks = 0; ks < 2; ++ks) {
            const int kk = ks * 32 + l4 * 8;
            int rA = wr * 16 + l15;
            bf16x8 av = *(const bf16x8*)&As[(rA * BK + kk) ^ ((rA & 7) << 3)];
            bf16x8 bv[NC];
#pragma unroll
            for (int nc = 0; nc < NC; ++nc) {
                int rB = wc * (N / 2) + nc * 16 + l15;
                bv[nc] = *(const bf16x8*)&Ws[(rB * BK + kk) ^ ((rB & 7) << 3)];
            }
#pragma unroll
            for (int nc = 0; nc < NC; ++nc)
                acc[nc] = __builtin_amdgcn_mfma_f32_16x16x32_bf16(
                    av, bv[nc], acc[nc], 0, 0, 0);
        }
        __syncthreads();
    }

#pragma unroll
    for (int nc = 0; nc < NC; ++nc) {
        int gn = wc * (N / 2) + nc * 16 + l15;
#pragma unroll
        for (int j = 0; j < 4; ++j) {
            int gm = m0 + wr * 16 + l4 * 4 + j;
            float v = acc[nc][j];
            if (EPI == 0) {
                v += bias[gn];
                v = fmaxf(v, 0.f);
                ((ushort*)Cout)[(long)gm * N + gn] = f2bf(v);
            } else if (EPI == 1) {
                v = fmaxf(v, 0.f);
                v = 0.8f * v + 0.1f * bf2f(pre[(long)gm * N + gn])
                             + 0.1f * bf2f(in0[(long)gm * N + gn]);
                ((ushort*)Cout)[(long)gm * N + gn] = f2bf(v);
            } else {
                v += bias[gn];
                v = fmaxf(v, 0.f);
                ((float*)Cout)[(long)gm * N + gn] = v;
            }
        }
    }
}

// ---------------------------------------------------------------------------
// Gather v3: full-row uint4 loads. Block = 16 nodes x 16 lanes, grid 1250.
// Lane owns 8 channels (one uint4 = 16 B); a 16-lane group covers the whole
// 256-B feats row in ONE wave-load pass -> wave-load instruction count is
// HALF of the uint2/h-half variant at identical total bytes.
// Pre-scaled weights in LDS (8 KB); indices type-sorted in LDS (8 KB).
// __launch_bounds__(256,4): VGPR cap 128 for deep load batching.
// ---------------------------------------------------------------------------
__global__ __launch_bounds__(256, 4) void gather_bf16(
    const uint4* __restrict__ feats_q,  // [NN][16] (16 B chunks of bf16 rows)
    const int* __restrict__ paths,      // [P][NN][L]
    const int* __restrict__ ptypes,     // [P]
    const float* __restrict__ pw,       // [2][L][HID] f32
    uint4* __restrict__ fout_q)         // [NN][32] (16 B chunks)
{
    const int nbase = (int)blockIdx.x * 16;
    const int tid = threadIdx.x;
    const int node = tid >> 4;          // 0..15
    const int l16 = tid & 15;           // 16-B chunk within row: channels l16*8..+8
    const int n = nbase + node;

    __shared__ int idx_l[16][N_TYPES][PATH_LEN][8];     // 8 KB
    __shared__ float wls[N_TYPES][PATH_LEN][HID];       // 8 KB, pre-scaled

    uint tmask = 0;
#pragma unroll
    for (int p = 0; p < N_PATHS; ++p) tmask |= (uint)(ptypes[p] != 0) << p;
    const int cnt1 = __popc(tmask);
    const int cnt0 = N_PATHS - cnt1;
    const float inv0 = cnt0 ? 1.f / (float)cnt0 : 0.f;
    const float inv1 = cnt1 ? 1.f / (float)cnt1 : 0.f;

    // stage 16 nodes x 64 indices, sorted by (type, l, rank)
#pragma unroll
    for (int j = 0; j < 4; ++j) {
        int li = tid * 4 + j;           // 0..1023
        int nd = li >> 6, k = li & 63, p = k >> 3, l = k & 7;
        int tp = (int)((tmask >> p) & 1u);
        uint below = tmask & ((1u << p) - 1u);
        int rank = tp ? __popc(below) : p - __popc(below);
        idx_l[nd][tp][l][rank] =
            __builtin_nontemporal_load(&paths[((long)p * NN + nbase + nd) * PATH_LEN + l]);
    }
    // stage pre-scaled weights: 2048 floats, 8 per thread
#pragma unroll
    for (int i = tid; i < N_TYPES * PATH_LEN * HID; i += 256) {
        int e = i >> 10;
        float s = e ? inv1 : inv0;
        ((float*)wls)[i] = ((const float*)pw)[i] * s;
    }
    __syncthreads();

    f32x4 outv[2][2];   // [e][lo/hi 4-channel groups]

#pragma unroll
    for (int e = 0; e < 2; ++e) {
        const int ce = e ? cnt1 : cnt0;
        f32x4 alo = {0.f, 0.f, 0.f, 0.f}, ahi = {0.f, 0.f, 0.f, 0.f};
        if (ce == 4) {
            // 4 pairs of l; per pair: 8 independent uint4 loads in flight
#pragma unroll
            for (int lp = 0; lp < 4; ++lp) {
                int4 ra = *(const int4*)&idx_l[node][e][lp * 2][0];
                int4 rb = *(const int4*)&idx_l[node][e][lp * 2 + 1][0];
                uint4 ga0 = feats_q[(long)ra.x * 16 + l16];
                uint4 ga1 = feats_q[(long)ra.y * 16 + l16];
                uint4 ga2 = feats_q[(long)ra.z * 16 + l16];
                uint4 ga3 = feats_q[(long)ra.w * 16 + l16];
                uint4 gb0 = feats_q[(long)rb.x * 16 + l16];
                uint4 gb1 = feats_q[(long)rb.y * 16 + l16];
                uint4 gb2 = feats_q[(long)rb.z * 16 + l16];
                uint4 gb3 = feats_q[(long)rb.w * 16 + l16];
#define SUM4(G0, G1, G2, G3, COMP, LO, HI)                                   \
                {                                                            \
                    LO = bf2f((ushort)(G0.COMP & 0xffff)) + bf2f((ushort)(G1.COMP & 0xffff)) \
                       + bf2f((ushort)(G2.COMP & 0xffff)) + bf2f((ushort)(G3.COMP & 0xffff)); \
                    HI = bf2f((ushort)(G0.COMP >> 16)) + bf2f((ushort)(G1.COMP >> 16)) \
                       + bf2f((ushort)(G2.COMP >> 16)) + bf2f((ushort)(G3.COMP >> 16)); \
                }
#define CONSUME(G0, G1, G2, G3, L)                                           \
                {                                                            \
                    const float* wp = &wls[e][L][l16 * 8];                   \
                    float s0, s1, s2, s3, s4, s5, s6, s7;                    \
                    SUM4(G0, G1, G2, G3, x, s0, s1);                         \
                    SUM4(G0, G1, G2, G3, y, s2, s3);                         \
                    SUM4(G0, G1, G2, G3, z, s4, s5);                         \
                    SUM4(G0, G1, G2, G3, w, s6, s7);                         \
                    alo[0] += s0 * wp[0]; alo[1] += s1 * wp[1];              \
                    alo[2] += s2 * wp[2]; alo[3] += s3 * wp[3];              \
                    ahi[0] += s4 * wp[4]; ahi[1] += s5 * wp[5];              \
                    ahi[2] += s6 * wp[6]; ahi[3] += s7 * wp[7];              \
                }
                CONSUME(ga0, ga1, ga2, ga3, lp * 2);
                CONSUME(gb0, gb1, gb2, gb3, lp * 2 + 1);
#undef CONSUME
#undef SUM4
            }
        } else {
            // generic fallback for any type distribution
#pragma unroll
            for (int l = 0; l < PATH_LEN; ++l) {
                float s[8] = {0.f, 0.f, 0.f, 0.f, 0.f, 0.f, 0.f, 0.f};
                for (int q = 0; q < ce; ++q) {
                    int row = idx_l[node][e][l][q];
                    uint4 g = feats_q[(long)row * 16 + l16];
                    s[0] += bf2f((ushort)(g.x & 0xffff));
                    s[1] += bf2f((ushort)(g.x >> 16));
                    s[2] += bf2f((ushort)(g.y & 0xffff));
                    s[3] += bf2f((ushort)(g.y >> 16));
                    s[4] += bf2f((ushort)(g.z & 0xffff));
                    s[5] += bf2f((ushort)(g.z >> 16));
                    s[6] += bf2f((ushort)(g.w & 0xffff));
                    s[7] += bf2f((ushort)(g.w >> 16));
                }
                const float* wp = &wls[e][l][l16 * 8];
#pragma unroll
                for (int c = 0; c < 4; ++c) alo[c] += s[c] * wp[c];
#pragma unroll
                for (int c = 0; c < 4; ++c) ahi[c] += s[4 + c] * wp[4 + c];
            }
        }
        outv[e][0] = alo;
        outv[e][1] = ahi;
    }

#pragma unroll
    for (int e = 0; e < 2; ++e) {
        uint4 o;
        o.x = (uint)f2bf(outv[e][0][0]) | ((uint)f2bf(outv[e][0][1]) << 16);
        o.y = (uint)f2bf(outv[e][0][2]) | ((uint)f2bf(outv[e][0][3]) << 16);
        o.z = (uint)f2bf(outv[e][1][0]) | ((uint)f2bf(outv[e][1][1]) << 16);
        o.w = (uint)f2bf(outv[e][1][2]) | ((uint)f2bf(outv[e][1][3]) << 16);
        fout_q[(long)n * 32 + e * 16 + l16] = o;   // cached: GEMM reads it next
    }
}

// ---------------------------------------------------------------------------
extern "C" void kernel_launch(void* const* d_in, const int* in_sizes, int n_in,
                              void* d_out, int out_size, void* d_ws, size_t ws_size,
                              hipStream_t stream)
{
    const float* input_x      = (const float*)d_in[0];
    const int*   paths        = (const int*)d_in[1];
    const int*   path_types   = (const int*)d_in[2];
    const float* fc_in_w      = (const float*)d_in[3];
    const float* fc_in_b      = (const float*)d_in[4];
    const float* fc_out_w     = (const float*)d_in[5];
    const float* fc_out_b     = (const float*)d_in[6];
    const float* layer_fc_w   = (const float*)d_in[7];
    const float* path_weights = (const float*)d_in[8];
    float* out = (float*)d_out;

    char* p = (char*)d_ws;
    ushort* w_in     = (ushort*)p; p += HID * IN_DIM * 2;                   // 64 KB
    ushort* w_layer  = (ushort*)p; p += N_LAYERS * HID * N_TYPES * HID * 2; // 256 KB
    ushort* w_out    = (ushort*)p; p += OUT_DIM * HID * 2;                  // 16 KB
    ushort* in_feats = (ushort*)p; p += (long)NN * HID * 2;                 // 5.12 MB
    ushort* featsA   = (ushort*)p; p += (long)NN * HID * 2;
    ushort* featsB   = (ushort*)p; p += (long)NN * HID * 2;
    ushort* fout     = (ushort*)p; p += (long)NN * N_TYPES * HID * 2;       // 10.24 MB

    cvt_weights<<<168, 256, 0, stream>>>(fc_in_w, layer_fc_w, fc_out_w,
                                         w_in, w_layer, w_out);

    const int GG = NN / 32;              // 625 (exact)
    const int GATHER_GRID = NN / 16;     // 1250

    gemm_mfma<HID, IN_DIM, 0, true><<<GG, 256, 0, stream>>>(
        input_x, w_in, fc_in_b, nullptr, nullptr, in_feats, NN);

    const ushort* src = in_feats;
    ushort* dsts[N_LAYERS] = {featsA, featsB, featsA, featsB};
    for (int i = 0; i < N_LAYERS; ++i) {
        gather_bf16<<<GATHER_GRID, 256, 0, stream>>>(
            (const uint4*)src, paths, path_types,
            path_weights + (long)i * N_TYPES * PATH_LEN * HID, (uint4*)fout);
        gemm_mfma<HID, N_TYPES * HID, 1, false><<<GG, 256, 0, stream>>>(
            fout, w_layer + (long)i * HID * N_TYPES * HID, nullptr,
            src, in_feats, dsts[i], NN);
        src = dsts[i];
    }

    gemm_mfma<OUT_DIM, HID, 2, false><<<GG, 256, 0, stream>>>(
        src, w_out, fc_out_b, nullptr, nullptr, out, NN);
}

// Round 11
// 174.800 us; speedup vs baseline: 1.6444x; 1.6444x over previous
//
#include <hip/hip_runtime.h>

#define NN 20000
#define IN_DIM 256
#define HID 128
#define OUT_DIM 64
#define N_LAYERS 4
#define N_PATHS 8
#define PATH_LEN 8
#define N_TYPES 2

typedef __attribute__((ext_vector_type(8))) short bf16x8;
typedef __attribute__((ext_vector_type(4))) float f32x4;

__device__ __forceinline__ float bf2f(ushort u) {
    union { uint u; float f; } c; c.u = ((uint)u) << 16; return c.f;
}
__device__ __forceinline__ ushort f2bf(float f) {
    union { float f; uint u; } c; c.f = f;
    uint u = c.u;
    uint lsb = (u >> 16) & 1;
    u += 0x7fffu + lsb;          // round-to-nearest-even (inputs finite)
    return (ushort)(u >> 16);
}

// ---------------------------------------------------------------------------
// One-shot fp32 -> bf16 conversion of all weight matrices (quad-per-thread).
// ---------------------------------------------------------------------------
__global__ __launch_bounds__(256) void cvt_weights(
    const float* __restrict__ w_in, const float* __restrict__ w_layer,
    const float* __restrict__ w_out,
    ushort* __restrict__ o_in, ushort* __restrict__ o_layer,
    ushort* __restrict__ o_out)
{
    int i = blockIdx.x * 256 + threadIdx.x;
    const float* s; ushort* d; int off;
    if (i < 8192)        { s = w_in;    d = o_in;    off = i; }
    else if (i < 40960)  { s = w_layer; d = o_layer; off = i - 8192; }
    else if (i < 43008)  { s = w_out;   d = o_out;   off = i - 40960; }
    else return;
    float4 v = ((const float4*)s)[off];
    ushort4 o;
    o.x = f2bf(v.x); o.y = f2bf(v.y); o.z = f2bf(v.z); o.w = f2bf(v.w);
    ((ushort4*)d)[off] = o;
}

// ---------------------------------------------------------------------------
// bf16 MFMA GEMM: C = epilogue(A[M,K] @ W[N,K]^T), fp32 accumulate.
// BM=32 (grid 625 on 256 CUs -> no 313-block quantization stall).
// 4 waves: wr = w>>1 (16-row blocks), wc = w&1 (N/2-col halves).
// LDS XOR-swizzle on 16B granules: elem ^= (row&7)<<3 (T2, conflict-free).
// AF32: A operand is fp32 in global, converted to bf16 while staging.
// EPI 0: bf16 out = relu(acc + bias[n])
// EPI 1: bf16 out = 0.8*relu(acc) + 0.1*pre + 0.1*in0
// EPI 2: f32  out = relu(acc + bias[n])
// M must be a multiple of 32 (20000 = 625*32).
// ---------------------------------------------------------------------------
template <int N, int K, int EPI, bool AF32>
__global__ __launch_bounds__(256) void gemm_mfma(
    const void* __restrict__ Ap,
    const ushort* __restrict__ W,     // [N][K] bf16
    const float* __restrict__ bias,
    const ushort* __restrict__ pre,
    const ushort* __restrict__ in0,
    void* __restrict__ Cout,
    int M)
{
    constexpr int BM = 32, BK = 64;
    constexpr int NC = N / 32;              // col-frags per wave (4 or 2)

    __shared__ short As[BM * BK];           // 4 KB
    __shared__ short Ws[N * BK];            // 16 KB (N=128) / 8 KB (N=64)

    const int tid = threadIdx.x;
    const int lane = tid & 63;
    const int w = tid >> 6;
    const int wr = w >> 1, wc = w & 1;
    const int m0 = blockIdx.x * BM;
    const int l15 = lane & 15, l4 = lane >> 4;

    f32x4 acc[NC];
#pragma unroll
    for (int nc = 0; nc < NC; ++nc)
#pragma unroll
        for (int j = 0; j < 4; ++j) acc[nc][j] = 0.f;

    for (int k0 = 0; k0 < K; k0 += BK) {
        // ---- stage A tile: 256 granules, exactly 1 per thread ----
        {
            int r = tid >> 3, kc = tid & 7;
            int gr = m0 + r;
            bf16x8 v;
            if constexpr (AF32) {
                const float* Af = (const float*)Ap;
                float4 v0 = *(const float4*)(Af + (long)gr * K + k0 + kc * 8);
                float4 v1 = *(const float4*)(Af + (long)gr * K + k0 + kc * 8 + 4);
                v[0] = (short)f2bf(v0.x); v[1] = (short)f2bf(v0.y);
                v[2] = (short)f2bf(v0.z); v[3] = (short)f2bf(v0.w);
                v[4] = (short)f2bf(v1.x); v[5] = (short)f2bf(v1.y);
                v[6] = (short)f2bf(v1.z); v[7] = (short)f2bf(v1.w);
            } else {
                v = *(const bf16x8*)((const ushort*)Ap + (long)gr * K + k0 + kc * 8);
            }
            int di = (tid * 8) ^ ((r & 7) << 3);
            *(bf16x8*)&As[di] = v;
        }
        // ---- stage W tile (bf16) ----
#pragma unroll
        for (int c = tid; c < N * 8; c += 256) {
            int r = c >> 3, kc = c & 7;
            bf16x8 v = *(const bf16x8*)(W + (long)r * K + k0 + kc * 8);
            int di = (r * BK + kc * 8) ^ ((r & 7) << 3);
            *(bf16x8*)&Ws[di] = v;
        }
        __syncthreads();

#pragma unroll
        for (int ks = 0; ks < 2; ++ks) {
            const int kk = ks * 32 + l4 * 8;
            int rA = wr * 16 + l15;
            bf16x8 av = *(const bf16x8*)&As[(rA * BK + kk) ^ ((rA & 7) << 3)];
            bf16x8 bv[NC];
#pragma unroll
            for (int nc = 0; nc < NC; ++nc) {
                int rB = wc * (N / 2) + nc * 16 + l15;
                bv[nc] = *(const bf16x8*)&Ws[(rB * BK + kk) ^ ((rB & 7) << 3)];
            }
#pragma unroll
            for (int nc = 0; nc < NC; ++nc)
                acc[nc] = __builtin_amdgcn_mfma_f32_16x16x32_bf16(
                    av, bv[nc], acc[nc], 0, 0, 0);
        }
        __syncthreads();
    }

#pragma unroll
    for (int nc = 0; nc < NC; ++nc) {
        int gn = wc * (N / 2) + nc * 16 + l15;
#pragma unroll
        for (int j = 0; j < 4; ++j) {
            int gm = m0 + wr * 16 + l4 * 4 + j;
            float v = acc[nc][j];
            if (EPI == 0) {
                v += bias[gn];
                v = fmaxf(v, 0.f);
                ((ushort*)Cout)[(long)gm * N + gn] = f2bf(v);
            } else if (EPI == 1) {
                v = fmaxf(v, 0.f);
                v = 0.8f * v + 0.1f * bf2f(pre[(long)gm * N + gn])
                             + 0.1f * bf2f(in0[(long)gm * N + gn]);
                ((ushort*)Cout)[(long)gm * N + gn] = f2bf(v);
            } else {
                v += bias[gn];
                v = fmaxf(v, 0.f);
                ((float*)Cout)[(long)gm * N + gn] = v;
            }
        }
    }
}

// ---------------------------------------------------------------------------
// Gather (round-9 proven best, ~33 us/layer): uint2 half-row loads (exactly
// one 128-B L2 line per 16-lane group), h-half split across blockIdx, fout
// stores and paths loads NONTEMPORAL (keep L2 read-pure for feats — cached
// fout stores write-allocate and evict feats: +80 MB fabric, round 10).
// Block = 16 nodes x 16 lanes; grid = 2*(NN/16).
// Pre-scaled weights in LDS; batched independent loads; VGPR cap 128.
// ---------------------------------------------------------------------------
__global__ __launch_bounds__(256, 4) void gather_bf16(
    const uint* __restrict__ feats_u,   // [NN][64]  (bf16x2 packed)
    const int* __restrict__ paths,      // [P][NN][L]
    const int* __restrict__ ptypes,     // [P]
    const float* __restrict__ pw,       // [2][L][HID] f32
    uint* __restrict__ fout_u)          // [NN][128] (bf16x2 packed)
{
    const int gb = (int)blockIdx.x;
    const int h_half = gb / (NN / 16);
    const int ntile = gb % (NN / 16);
    const int nbase = ntile * 16;

    const int tid = threadIdx.x;
    const int node = tid >> 4;          // 0..15
    const int l16 = tid & 15;           // channel quad within the h-half
    const int n = nbase + node;

    __shared__ int idx_l[16][N_TYPES][PATH_LEN][8];     // 8 KB
    __shared__ float wls[N_TYPES][PATH_LEN][64];        // 4 KB, pre-scaled

    uint tmask = 0;
#pragma unroll
    for (int p = 0; p < N_PATHS; ++p) tmask |= (uint)(ptypes[p] != 0) << p;
    const int cnt1 = __popc(tmask);
    const int cnt0 = N_PATHS - cnt1;
    const float inv0 = cnt0 ? 1.f / (float)cnt0 : 0.f;
    const float inv1 = cnt1 ? 1.f / (float)cnt1 : 0.f;

    // stage 16 nodes x 64 indices, sorted by (type, l, rank); nontemporal
#pragma unroll
    for (int j = 0; j < 4; ++j) {
        int li = tid * 4 + j;           // 0..1023
        int nd = li >> 6, k = li & 63, p = k >> 3, l = k & 7;
        int tp = (int)((tmask >> p) & 1u);
        uint below = tmask & ((1u << p) - 1u);
        int rank = tp ? __popc(below) : p - __popc(below);
        idx_l[nd][tp][l][rank] =
            __builtin_nontemporal_load(&paths[((long)p * NN + nbase + nd) * PATH_LEN + l]);
    }
    // stage pre-scaled weights for this h-half: 256 float4s, 1 per thread
    {
        int e = tid >> 7, l = (tid >> 4) & 7, c4 = tid & 15;
        float s = e ? inv1 : inv0;
        float4 t = *(const float4*)&pw[(e * PATH_LEN + l) * HID + h_half * 64 + c4 * 4];
        t.x *= s; t.y *= s; t.z *= s; t.w *= s;
        *(float4*)&wls[e][l][c4 * 4] = t;
    }
    __syncthreads();

    const long coff = h_half * 32 + l16 * 2;   // uint offset within a row
    float4 out[2];

#pragma unroll
    for (int e = 0; e < 2; ++e) {
        const int ce = e ? cnt1 : cnt0;
        float4 acc = {0.f, 0.f, 0.f, 0.f};
        if (ce == 4) {
            // prefetch all 8 index quads (independent LDS reads)
            int4 r[PATH_LEN];
#pragma unroll
            for (int l = 0; l < PATH_LEN; ++l)
                r[l] = *(const int4*)&idx_l[node][e][l][0];
            // two batches of 16 independent global loads each
#pragma unroll
            for (int half = 0; half < 2; ++half) {
                uint2 g[4][4];
#pragma unroll
                for (int l = 0; l < 4; ++l) {
                    int4 rr = r[half * 4 + l];
                    g[l][0] = *(const uint2*)(feats_u + (long)rr.x * 64 + coff);
                    g[l][1] = *(const uint2*)(feats_u + (long)rr.y * 64 + coff);
                    g[l][2] = *(const uint2*)(feats_u + (long)rr.z * 64 + coff);
                    g[l][3] = *(const uint2*)(feats_u + (long)rr.w * 64 + coff);
                }
#pragma unroll
                for (int l = 0; l < 4; ++l) {
                    float sx = bf2f((ushort)(g[l][0].x & 0xffff)) + bf2f((ushort)(g[l][1].x & 0xffff))
                             + bf2f((ushort)(g[l][2].x & 0xffff)) + bf2f((ushort)(g[l][3].x & 0xffff));
                    float sy = bf2f((ushort)(g[l][0].x >> 16)) + bf2f((ushort)(g[l][1].x >> 16))
                             + bf2f((ushort)(g[l][2].x >> 16)) + bf2f((ushort)(g[l][3].x >> 16));
                    float sz = bf2f((ushort)(g[l][0].y & 0xffff)) + bf2f((ushort)(g[l][1].y & 0xffff))
                             + bf2f((ushort)(g[l][2].y & 0xffff)) + bf2f((ushort)(g[l][3].y & 0xffff));
                    float sw = bf2f((ushort)(g[l][0].y >> 16)) + bf2f((ushort)(g[l][1].y >> 16))
                             + bf2f((ushort)(g[l][2].y >> 16)) + bf2f((ushort)(g[l][3].y >> 16));
                    const float4 wv = *(const float4*)&wls[e][half * 4 + l][l16 * 4];
                    acc.x += sx * wv.x;
                    acc.y += sy * wv.y;
                    acc.z += sz * wv.z;
                    acc.w += sw * wv.w;
                }
            }
        } else {
            // generic fallback for any type distribution
#pragma unroll
            for (int l = 0; l < PATH_LEN; ++l) {
                float sx = 0.f, sy = 0.f, sz = 0.f, sw = 0.f;
                for (int q = 0; q < ce; ++q) {
                    int row = idx_l[node][e][l][q];
                    uint2 v = *(const uint2*)(feats_u + (long)row * 64 + coff);
                    sx += bf2f((ushort)(v.x & 0xffff));
                    sy += bf2f((ushort)(v.x >> 16));
                    sz += bf2f((ushort)(v.y & 0xffff));
                    sw += bf2f((ushort)(v.y >> 16));
                }
                const float4 wv = *(const float4*)&wls[e][l][l16 * 4];
                acc.x += sx * wv.x;
                acc.y += sy * wv.y;
                acc.z += sz * wv.z;
                acc.w += sw * wv.w;
            }
        }
        out[e] = acc;
    }

#pragma unroll
    for (int e = 0; e < 2; ++e) {
        uint2 o;
        o.x = (uint)f2bf(out[e].x) | ((uint)f2bf(out[e].y) << 16);
        o.y = (uint)f2bf(out[e].z) | ((uint)f2bf(out[e].w) << 16);
        unsigned long long packed = (unsigned long long)o.x
                                  | ((unsigned long long)o.y << 32);
        __builtin_nontemporal_store(packed,
            (unsigned long long*)(fout_u + (long)n * 128 + e * 64 + coff));
    }
}

// ---------------------------------------------------------------------------
extern "C" void kernel_launch(void* const* d_in, const int* in_sizes, int n_in,
                              void* d_out, int out_size, void* d_ws, size_t ws_size,
                              hipStream_t stream)
{
    const float* input_x      = (const float*)d_in[0];
    const int*   paths        = (const int*)d_in[1];
    const int*   path_types   = (const int*)d_in[2];
    const float* fc_in_w      = (const float*)d_in[3];
    const float* fc_in_b      = (const float*)d_in[4];
    const float* fc_out_w     = (const float*)d_in[5];
    const float* fc_out_b     = (const float*)d_in[6];
    const float* layer_fc_w   = (const float*)d_in[7];
    const float* path_weights = (const float*)d_in[8];
    float* out = (float*)d_out;

    char* p = (char*)d_ws;
    ushort* w_in     = (ushort*)p; p += HID * IN_DIM * 2;                   // 64 KB
    ushort* w_layer  = (ushort*)p; p += N_LAYERS * HID * N_TYPES * HID * 2; // 256 KB
    ushort* w_out    = (ushort*)p; p += OUT_DIM * HID * 2;                  // 16 KB
    ushort* in_feats = (ushort*)p; p += (long)NN * HID * 2;                 // 5.12 MB
    ushort* featsA   = (ushort*)p; p += (long)NN * HID * 2;
    ushort* featsB   = (ushort*)p; p += (long)NN * HID * 2;
    ushort* fout     = (ushort*)p; p += (long)NN * N_TYPES * HID * 2;       // 10.24 MB

    cvt_weights<<<168, 256, 0, stream>>>(fc_in_w, layer_fc_w, fc_out_w,
                                         w_in, w_layer, w_out);

    const int GG = NN / 32;                 // 625 (exact)
    const int GATHER_GRID = (NN / 16) * 2;  // 2500

    gemm_mfma<HID, IN_DIM, 0, true><<<GG, 256, 0, stream>>>(
        input_x, w_in, fc_in_b, nullptr, nullptr, in_feats, NN);

    const ushort* src = in_feats;
    ushort* dsts[N_LAYERS] = {featsA, featsB, featsA, featsB};
    for (int i = 0; i < N_LAYERS; ++i) {
        gather_bf16<<<GATHER_GRID, 256, 0, stream>>>(
            (const uint*)src, paths, path_types,
            path_weights + (long)i * N_TYPES * PATH_LEN * HID, (uint*)fout);
        gemm_mfma<HID, N_TYPES * HID, 1, false><<<GG, 256, 0, stream>>>(
            fout, w_layer + (long)i * HID * N_TYPES * HID, nullptr,
            src, in_feats, dsts[i], NN);
        src = dsts[i];
    }

    gemm_mfma<OUT_DIM, HID, 2, false><<<GG, 256, 0, stream>>>(
        src, w_out, fc_out_b, nullptr, nullptr, out, NN);
}

// Round 13
// 170.909 us; speedup vs baseline: 1.6819x; 1.0228x over previous
//
#include <hip/hip_runtime.h>

#define NN 20000
#define IN_DIM 256
#define HID 128
#define OUT_DIM 64
#define N_LAYERS 4
#define N_PATHS 8
#define PATH_LEN 8
#define N_TYPES 2

typedef __attribute__((ext_vector_type(8))) short bf16x8;
typedef __attribute__((ext_vector_type(4))) float f32x4;

__device__ __forceinline__ float bf2f(ushort u) {
    union { uint u; float f; } c; c.u = ((uint)u) << 16; return c.f;
}
__device__ __forceinline__ ushort f2bf(float f) {
    union { float f; uint u; } c; c.f = f;
    uint u = c.u;
    uint lsb = (u >> 16) & 1;
    u += 0x7fffu + lsb;          // round-to-nearest-even (inputs finite)
    return (ushort)(u >> 16);
}

// ---------------------------------------------------------------------------
// bf16 MFMA GEMM: C = epilogue(A[M,K] @ W[N,K]^T), fp32 accumulate.
// BM=32, grid 625 (no block-quantization stall). 4 waves: wr=w>>1, wc=w&1.
// LDS XOR-swizzle on 16B granules: elem ^= (row&7)<<3 (T2, conflict-free).
// AF32 / WF32: operand is fp32 in global, converted to bf16 while staging.
// CVT: blocks side-convert w_layer + w_out (fp32->bf16) at kernel entry.
// EPI 0: bf16 out = relu(acc + bias[n]);  EPI 1: bf16 out = residual mix.
// FUSE_OUT (with EPI 1): block then computes out32x64 = relu(dst@Wout^T + b)
// via an LDS round-trip of its dst tile - fc_out fused into layer-4 GEMM.
// ---------------------------------------------------------------------------
template <int N, int K, int EPI, bool AF32, bool WF32, bool CVT, bool FUSE_OUT>
__global__ __launch_bounds__(256) void gemm_mfma(
    const void* __restrict__ Ap,
    const void* __restrict__ Wp,       // [N][K] bf16 (or fp32 if WF32)
    const float* __restrict__ bias,
    const ushort* __restrict__ pre,
    const ushort* __restrict__ in0,
    void* __restrict__ Cout,
    int M,
    const float* __restrict__ cvt_s1, ushort* __restrict__ cvt_d1,  // w_layer
    const float* __restrict__ cvt_s2, ushort* __restrict__ cvt_d2,  // w_out
    const ushort* __restrict__ Wtail,  // [OUT_DIM][HID] bf16 (FUSE_OUT)
    const float* __restrict__ bias_tail,
    float* __restrict__ out_tail)
{
    constexpr int BM = 32, BK = 64;
    constexpr int NC = N / 32;

    // LDS: As 4K + Ws 16K during K-loop; FUSE_OUT tail overlays:
    // Dt (bf16 32x128, 8K) at 0, Wt (bf16 64x128, 16K) at 8K -> 24K total.
    constexpr int SMEM = FUSE_OUT ? 24576 : (4096 + N * BK * 2);
    __shared__ __align__(16) char smem[SMEM];
    short* As = (short*)smem;                 // [32*64]
    short* Ws = (short*)(smem + 4096);        // [N*64]

    const int tid = threadIdx.x;

    if constexpr (CVT) {
        // one-shot side conversion: w_layer (32768 quads) + w_out (2048)
        int i = (int)blockIdx.x * 256 + tid;
        if (i < 32768) {
            float4 v = ((const float4*)cvt_s1)[i];
            ushort4 o; o.x = f2bf(v.x); o.y = f2bf(v.y);
            o.z = f2bf(v.z); o.w = f2bf(v.w);
            ((ushort4*)cvt_d1)[i] = o;
        } else if (i < 34816) {
            float4 v = ((const float4*)cvt_s2)[i - 32768];
            ushort4 o; o.x = f2bf(v.x); o.y = f2bf(v.y);
            o.z = f2bf(v.z); o.w = f2bf(v.w);
            ((ushort4*)cvt_d2)[i - 32768] = o;
        }
    }

    const int lane = tid & 63;
    const int w = tid >> 6;
    const int wr = w >> 1, wc = w & 1;
    const int m0 = blockIdx.x * BM;
    const int l15 = lane & 15, l4 = lane >> 4;

    f32x4 acc[NC];
#pragma unroll
    for (int nc = 0; nc < NC; ++nc)
#pragma unroll
        for (int j = 0; j < 4; ++j) acc[nc][j] = 0.f;

    for (int k0 = 0; k0 < K; k0 += BK) {
        // ---- stage A tile: 256 granules, 1 per thread ----
        {
            int r = tid >> 3, kc = tid & 7;
            int gr = m0 + r;
            bf16x8 v;
            if constexpr (AF32) {
                const float* Af = (const float*)Ap;
                float4 v0 = *(const float4*)(Af + (long)gr * K + k0 + kc * 8);
                float4 v1 = *(const float4*)(Af + (long)gr * K + k0 + kc * 8 + 4);
                v[0] = (short)f2bf(v0.x); v[1] = (short)f2bf(v0.y);
                v[2] = (short)f2bf(v0.z); v[3] = (short)f2bf(v0.w);
                v[4] = (short)f2bf(v1.x); v[5] = (short)f2bf(v1.y);
                v[6] = (short)f2bf(v1.z); v[7] = (short)f2bf(v1.w);
            } else {
                v = *(const bf16x8*)((const ushort*)Ap + (long)gr * K + k0 + kc * 8);
            }
            int di = (tid * 8) ^ ((r & 7) << 3);
            *(bf16x8*)&As[di] = v;
        }
        // ---- stage W tile ----
#pragma unroll
        for (int c = tid; c < N * 8; c += 256) {
            int r = c >> 3, kc = c & 7;
            bf16x8 v;
            if constexpr (WF32) {
                const float* Wf = (const float*)Wp;
                float4 v0 = *(const float4*)(Wf + (long)r * K + k0 + kc * 8);
                float4 v1 = *(const float4*)(Wf + (long)r * K + k0 + kc * 8 + 4);
                v[0] = (short)f2bf(v0.x); v[1] = (short)f2bf(v0.y);
                v[2] = (short)f2bf(v0.z); v[3] = (short)f2bf(v0.w);
                v[4] = (short)f2bf(v1.x); v[5] = (short)f2bf(v1.y);
                v[6] = (short)f2bf(v1.z); v[7] = (short)f2bf(v1.w);
            } else {
                v = *(const bf16x8*)((const ushort*)Wp + (long)r * K + k0 + kc * 8);
            }
            int di = (r * BK + kc * 8) ^ ((r & 7) << 3);
            *(bf16x8*)&Ws[di] = v;
        }
        __syncthreads();

#pragma unroll
        for (int ks = 0; ks < 2; ++ks) {
            const int kk = ks * 32 + l4 * 8;
            int rA = wr * 16 + l15;
            bf16x8 av = *(const bf16x8*)&As[(rA * BK + kk) ^ ((rA & 7) << 3)];
            bf16x8 bv[NC];
#pragma unroll
            for (int nc = 0; nc < NC; ++nc) {
                int rB = wc * (N / 2) + nc * 16 + l15;
                bv[nc] = *(const bf16x8*)&Ws[(rB * BK + kk) ^ ((rB & 7) << 3)];
            }
#pragma unroll
            for (int nc = 0; nc < NC; ++nc)
                acc[nc] = __builtin_amdgcn_mfma_f32_16x16x32_bf16(
                    av, bv[nc], acc[nc], 0, 0, 0);
        }
        __syncthreads();
    }

    // ---- epilogue ----
    short* Dt = (short*)smem;                 // FUSE_OUT: bf16 [32][128]
#pragma unroll
    for (int nc = 0; nc < NC; ++nc) {
        int gn = wc * (N / 2) + nc * 16 + l15;
#pragma unroll
        for (int j = 0; j < 4; ++j) {
            int gm = m0 + wr * 16 + l4 * 4 + j;
            float v = acc[nc][j];
            ushort bv16;
            if (EPI == 0) {
                v += bias[gn];
                v = fmaxf(v, 0.f);
                bv16 = f2bf(v);
                ((ushort*)Cout)[(long)gm * N + gn] = bv16;
            } else {
                v = fmaxf(v, 0.f);
                v = 0.8f * v + 0.1f * bf2f(pre[(long)gm * N + gn])
                             + 0.1f * bf2f(in0[(long)gm * N + gn]);
                bv16 = f2bf(v);
                ((ushort*)Cout)[(long)gm * N + gn] = bv16;
            }
            if constexpr (FUSE_OUT) {
                int row = wr * 16 + l4 * 4 + j;
                int e = row * 128 + gn;
                Dt[e ^ ((row & 7) << 3)] = (short)bv16;
            }
        }
    }

    if constexpr (FUSE_OUT) {
        // stage Wout [64][128] bf16 into Wt (swizzled): 1024 granules,
        // *** 16 granules per 128-elem row: r = c>>4, kc = c&15 ***
        // (round-12 bug: c>>3/c&7 decoded 64-elem rows -> OOB reads of Wtail)
        short* Wt = (short*)(smem + 8192);
        __syncthreads();   // Dt fully written; Ws/As dead
#pragma unroll
        for (int c = tid; c < 1024; c += 256) {
            int r = c >> 4, kc = c & 15;
            bf16x8 v = *(const bf16x8*)(Wtail + (long)r * HID + kc * 8);
            int di = (r * 128 + kc * 8) ^ ((r & 7) << 3);
            *(bf16x8*)&Wt[di] = v;
        }
        __syncthreads();

        // 32x64 = dst(32x128) @ Wout^T(64x128): 4 waves = 2 row x 2 col blocks
        const int wr2 = w >> 1, wc2 = w & 1;
        f32x4 acc2[2];
#pragma unroll
        for (int nc = 0; nc < 2; ++nc)
#pragma unroll
            for (int j = 0; j < 4; ++j) acc2[nc][j] = 0.f;

#pragma unroll
        for (int ksi = 0; ksi < 4; ++ksi) {
            const int kk = ksi * 32 + l4 * 8;
            int rA = wr2 * 16 + l15;
            bf16x8 av = *(const bf16x8*)&Dt[(rA * 128 + kk) ^ ((rA & 7) << 3)];
#pragma unroll
            for (int nc = 0; nc < 2; ++nc) {
                int rB = wc2 * 32 + nc * 16 + l15;
                bf16x8 bv = *(const bf16x8*)&Wt[(rB * 128 + kk) ^ ((rB & 7) << 3)];
                acc2[nc] = __builtin_amdgcn_mfma_f32_16x16x32_bf16(
                    av, bv, acc2[nc], 0, 0, 0);
            }
        }

#pragma unroll
        for (int nc = 0; nc < 2; ++nc) {
            int gn = wc2 * 32 + nc * 16 + l15;
#pragma unroll
            for (int j = 0; j < 4; ++j) {
                int gm = m0 + wr2 * 16 + l4 * 4 + j;
                float v = acc2[nc][j] + bias_tail[gn];
                out_tail[(long)gm * OUT_DIM + gn] = fmaxf(v, 0.f);
            }
        }
    }
}

// ---------------------------------------------------------------------------
// Gather (round-11 proven, ~30 us/layer): uint2 half-row loads (one 128-B L2
// line per 16-lane group), h-half split across blockIdx, nontemporal paths
// loads + fout stores (cached fout stores write-allocate and evict feats:
// +80 MB fabric, round 10). Block = 16 nodes x 16 lanes; grid = 2*(NN/16).
// Pre-scaled weights in LDS; batched independent loads; VGPR cap 128.
// ---------------------------------------------------------------------------
__global__ __launch_bounds__(256, 4) void gather_bf16(
    const uint* __restrict__ feats_u,   // [NN][64]  (bf16x2 packed)
    const int* __restrict__ paths,      // [P][NN][L]
    const int* __restrict__ ptypes,     // [P]
    const float* __restrict__ pw,       // [2][L][HID] f32
    uint* __restrict__ fout_u)          // [NN][128] (bf16x2 packed)
{
    const int gb = (int)blockIdx.x;
    const int h_half = gb / (NN / 16);
    const int ntile = gb % (NN / 16);
    const int nbase = ntile * 16;

    const int tid = threadIdx.x;
    const int node = tid >> 4;          // 0..15
    const int l16 = tid & 15;           // channel quad within the h-half
    const int n = nbase + node;

    __shared__ int idx_l[16][N_TYPES][PATH_LEN][8];     // 8 KB
    __shared__ float wls[N_TYPES][PATH_LEN][64];        // 4 KB, pre-scaled

    uint tmask = 0;
#pragma unroll
    for (int p = 0; p < N_PATHS; ++p) tmask |= (uint)(ptypes[p] != 0) << p;
    const int cnt1 = __popc(tmask);
    const int cnt0 = N_PATHS - cnt1;
    const float inv0 = cnt0 ? 1.f / (float)cnt0 : 0.f;
    const float inv1 = cnt1 ? 1.f / (float)cnt1 : 0.f;

    // stage 16 nodes x 64 indices, sorted by (type, l, rank); nontemporal
#pragma unroll
    for (int j = 0; j < 4; ++j) {
        int li = tid * 4 + j;           // 0..1023
        int nd = li >> 6, k = li & 63, p = k >> 3, l = k & 7;
        int tp = (int)((tmask >> p) & 1u);
        uint below = tmask & ((1u << p) - 1u);
        int rank = tp ? __popc(below) : p - __popc(below);
        idx_l[nd][tp][l][rank] =
            __builtin_nontemporal_load(&paths[((long)p * NN + nbase + nd) * PATH_LEN + l]);
    }
    // stage pre-scaled weights for this h-half: 256 float4s, 1 per thread
    {
        int e = tid >> 7, l = (tid >> 4) & 7, c4 = tid & 15;
        float s = e ? inv1 : inv0;
        float4 t = *(const float4*)&pw[(e * PATH_LEN + l) * HID + h_half * 64 + c4 * 4];
        t.x *= s; t.y *= s; t.z *= s; t.w *= s;
        *(float4*)&wls[e][l][c4 * 4] = t;
    }
    __syncthreads();

    const long coff = h_half * 32 + l16 * 2;   // uint offset within a row
    float4 out[2];

#pragma unroll
    for (int e = 0; e < 2; ++e) {
        const int ce = e ? cnt1 : cnt0;
        float4 acc = {0.f, 0.f, 0.f, 0.f};
        if (ce == 4) {
            int4 r[PATH_LEN];
#pragma unroll
            for (int l = 0; l < PATH_LEN; ++l)
                r[l] = *(const int4*)&idx_l[node][e][l][0];
#pragma unroll
            for (int half = 0; half < 2; ++half) {
                uint2 g[4][4];
#pragma unroll
                for (int l = 0; l < 4; ++l) {
                    int4 rr = r[half * 4 + l];
                    g[l][0] = *(const uint2*)(feats_u + (long)rr.x * 64 + coff);
                    g[l][1] = *(const uint2*)(feats_u + (long)rr.y * 64 + coff);
                    g[l][2] = *(const uint2*)(feats_u + (long)rr.z * 64 + coff);
                    g[l][3] = *(const uint2*)(feats_u + (long)rr.w * 64 + coff);
                }
#pragma unroll
                for (int l = 0; l < 4; ++l) {
                    float sx = bf2f((ushort)(g[l][0].x & 0xffff)) + bf2f((ushort)(g[l][1].x & 0xffff))
                             + bf2f((ushort)(g[l][2].x & 0xffff)) + bf2f((ushort)(g[l][3].x & 0xffff));
                    float sy = bf2f((ushort)(g[l][0].x >> 16)) + bf2f((ushort)(g[l][1].x >> 16))
                             + bf2f((ushort)(g[l][2].x >> 16)) + bf2f((ushort)(g[l][3].x >> 16));
                    float sz = bf2f((ushort)(g[l][0].y & 0xffff)) + bf2f((ushort)(g[l][1].y & 0xffff))
                             + bf2f((ushort)(g[l][2].y & 0xffff)) + bf2f((ushort)(g[l][3].y & 0xffff));
                    float sw = bf2f((ushort)(g[l][0].y >> 16)) + bf2f((ushort)(g[l][1].y >> 16))
                             + bf2f((ushort)(g[l][2].y >> 16)) + bf2f((ushort)(g[l][3].y >> 16));
                    const float4 wv = *(const float4*)&wls[e][half * 4 + l][l16 * 4];
                    acc.x += sx * wv.x;
                    acc.y += sy * wv.y;
                    acc.z += sz * wv.z;
                    acc.w += sw * wv.w;
                }
            }
        } else {
#pragma unroll
            for (int l = 0; l < PATH_LEN; ++l) {
                float sx = 0.f, sy = 0.f, sz = 0.f, sw = 0.f;
                for (int q = 0; q < ce; ++q) {
                    int row = idx_l[node][e][l][q];
                    uint2 v = *(const uint2*)(feats_u + (long)row * 64 + coff);
                    sx += bf2f((ushort)(v.x & 0xffff));
                    sy += bf2f((ushort)(v.x >> 16));
                    sz += bf2f((ushort)(v.y & 0xffff));
                    sw += bf2f((ushort)(v.y >> 16));
                }
                const float4 wv = *(const float4*)&wls[e][l][l16 * 4];
                acc.x += sx * wv.x;
                acc.y += sy * wv.y;
                acc.z += sz * wv.z;
                acc.w += sw * wv.w;
            }
        }
        out[e] = acc;
    }

#pragma unroll
    for (int e = 0; e < 2; ++e) {
        uint2 o;
        o.x = (uint)f2bf(out[e].x) | ((uint)f2bf(out[e].y) << 16);
        o.y = (uint)f2bf(out[e].z) | ((uint)f2bf(out[e].w) << 16);
        unsigned long long packed = (unsigned long long)o.x
                                  | ((unsigned long long)o.y << 32);
        __builtin_nontemporal_store(packed,
            (unsigned long long*)(fout_u + (long)n * 128 + e * 64 + coff));
    }
}

// ---------------------------------------------------------------------------
extern "C" void kernel_launch(void* const* d_in, const int* in_sizes, int n_in,
                              void* d_out, int out_size, void* d_ws, size_t ws_size,
                              hipStream_t stream)
{
    const float* input_x      = (const float*)d_in[0];
    const int*   paths        = (const int*)d_in[1];
    const int*   path_types   = (const int*)d_in[2];
    const float* fc_in_w      = (const float*)d_in[3];
    const float* fc_in_b      = (const float*)d_in[4];
    const float* fc_out_w     = (const float*)d_in[5];
    const float* fc_out_b     = (const float*)d_in[6];
    const float* layer_fc_w   = (const float*)d_in[7];
    const float* path_weights = (const float*)d_in[8];
    float* out = (float*)d_out;

    char* p = (char*)d_ws;
    ushort* w_layer  = (ushort*)p; p += N_LAYERS * HID * N_TYPES * HID * 2; // 256 KB
    ushort* w_out    = (ushort*)p; p += OUT_DIM * HID * 2;                  // 16 KB
    ushort* in_feats = (ushort*)p; p += (long)NN * HID * 2;                 // 5.12 MB
    ushort* featsA   = (ushort*)p; p += (long)NN * HID * 2;
    ushort* featsB   = (ushort*)p; p += (long)NN * HID * 2;
    ushort* fout     = (ushort*)p; p += (long)NN * N_TYPES * HID * 2;       // 10.24 MB

    const int GG = NN / 32;                 // 625 (exact)
    const int GATHER_GRID = (NN / 16) * 2;  // 2500

    // fc_in (A,W fp32 convert-on-stage) + side-convert w_layer / w_out
    gemm_mfma<HID, IN_DIM, 0, true, true, true, false><<<GG, 256, 0, stream>>>(
        input_x, fc_in_w, fc_in_b, nullptr, nullptr, in_feats, NN,
        layer_fc_w, w_layer, fc_out_w, w_out,
        nullptr, nullptr, nullptr);

    const ushort* src = in_feats;
    ushort* dsts[N_LAYERS] = {featsA, featsB, featsA, featsB};
    for (int i = 0; i < N_LAYERS; ++i) {
        gather_bf16<<<GATHER_GRID, 256, 0, stream>>>(
            (const uint*)src, paths, path_types,
            path_weights + (long)i * N_TYPES * PATH_LEN * HID, (uint*)fout);
        if (i < N_LAYERS - 1) {
            gemm_mfma<HID, N_TYPES * HID, 1, false, false, false, false>
                <<<GG, 256, 0, stream>>>(
                fout, w_layer + (long)i * HID * N_TYPES * HID, nullptr,
                src, in_feats, dsts[i], NN,
                nullptr, nullptr, nullptr, nullptr, nullptr, nullptr, nullptr);
        } else {
            // layer 4 + fused fc_out tail
            gemm_mfma<HID, N_TYPES * HID, 1, false, false, false, true>
                <<<GG, 256, 0, stream>>>(
                fout, w_layer + (long)i * HID * N_TYPES * HID, nullptr,
                src, in_feats, dsts[i], NN,
                nullptr, nullptr, nullptr, nullptr,
                w_out, fc_out_b, out);
        }
        src = dsts[i];
    }
}

// Round 14
// 169.661 us; speedup vs baseline: 1.6943x; 1.0074x over previous
//
#include <hip/hip_runtime.h>

#define NN 20000
#define IN_DIM 256
#define HID 128
#define OUT_DIM 64
#define N_LAYERS 4
#define N_PATHS 8
#define PATH_LEN 8
#define N_TYPES 2

typedef __attribute__((ext_vector_type(8))) short bf16x8;
typedef __attribute__((ext_vector_type(4))) float f32x4;

__device__ __forceinline__ float bf2f(ushort u) {
    union { uint u; float f; } c; c.u = ((uint)u) << 16; return c.f;
}
__device__ __forceinline__ ushort f2bf(float f) {
    union { float f; uint u; } c; c.f = f;
    uint u = c.u;
    uint lsb = (u >> 16) & 1;
    u += 0x7fffu + lsb;          // round-to-nearest-even (inputs finite)
    return (ushort)(u >> 16);
}

// ---------------------------------------------------------------------------
// bf16 MFMA GEMM: C = epilogue(A[M,K] @ W[N,K]^T), fp32 accumulate.
// BM=32, grid 625 (no block-quantization stall). 4 waves: wr=w>>1, wc=w&1.
// LDS XOR-swizzle on 16B granules: elem ^= (row&7)<<3 (T2, conflict-free).
// AF32 / WF32: operand is fp32 in global, converted to bf16 while staging.
// CVT: blocks side-convert w_layer + w_out (fp32->bf16) at kernel entry.
// EPI 0: bf16 out = relu(acc + bias[n]);  EPI 1: bf16 out = residual mix.
// FUSE_OUT (with EPI 1): block then computes out32x64 = relu(dst@Wout^T + b)
// via an LDS round-trip of its dst tile - fc_out fused into layer-4 GEMM.
// ---------------------------------------------------------------------------
template <int N, int K, int EPI, bool AF32, bool WF32, bool CVT, bool FUSE_OUT>
__global__ __launch_bounds__(256) void gemm_mfma(
    const void* __restrict__ Ap,
    const void* __restrict__ Wp,       // [N][K] bf16 (or fp32 if WF32)
    const float* __restrict__ bias,
    const ushort* __restrict__ pre,
    const ushort* __restrict__ in0,
    void* __restrict__ Cout,
    int M,
    const float* __restrict__ cvt_s1, ushort* __restrict__ cvt_d1,  // w_layer
    const float* __restrict__ cvt_s2, ushort* __restrict__ cvt_d2,  // w_out
    const ushort* __restrict__ Wtail,  // [OUT_DIM][HID] bf16 (FUSE_OUT)
    const float* __restrict__ bias_tail,
    float* __restrict__ out_tail)
{
    constexpr int BM = 32, BK = 64;
    constexpr int NC = N / 32;

    // LDS: As 4K + Ws 16K during K-loop; FUSE_OUT tail overlays:
    // Dt (bf16 32x128, 8K) at 0, Wt (bf16 64x128, 16K) at 8K -> 24K total.
    constexpr int SMEM = FUSE_OUT ? 24576 : (4096 + N * BK * 2);
    __shared__ __align__(16) char smem[SMEM];
    short* As = (short*)smem;                 // [32*64]
    short* Ws = (short*)(smem + 4096);        // [N*64]

    const int tid = threadIdx.x;

    if constexpr (CVT) {
        // one-shot side conversion: w_layer (32768 quads) + w_out (2048)
        int i = (int)blockIdx.x * 256 + tid;
        if (i < 32768) {
            float4 v = ((const float4*)cvt_s1)[i];
            ushort4 o; o.x = f2bf(v.x); o.y = f2bf(v.y);
            o.z = f2bf(v.z); o.w = f2bf(v.w);
            ((ushort4*)cvt_d1)[i] = o;
        } else if (i < 34816) {
            float4 v = ((const float4*)cvt_s2)[i - 32768];
            ushort4 o; o.x = f2bf(v.x); o.y = f2bf(v.y);
            o.z = f2bf(v.z); o.w = f2bf(v.w);
            ((ushort4*)cvt_d2)[i - 32768] = o;
        }
    }

    const int lane = tid & 63;
    const int w = tid >> 6;
    const int wr = w >> 1, wc = w & 1;
    const int m0 = blockIdx.x * BM;
    const int l15 = lane & 15, l4 = lane >> 4;

    f32x4 acc[NC];
#pragma unroll
    for (int nc = 0; nc < NC; ++nc)
#pragma unroll
        for (int j = 0; j < 4; ++j) acc[nc][j] = 0.f;

    for (int k0 = 0; k0 < K; k0 += BK) {
        // ---- stage A tile: 256 granules, 1 per thread ----
        {
            int r = tid >> 3, kc = tid & 7;
            int gr = m0 + r;
            bf16x8 v;
            if constexpr (AF32) {
                const float* Af = (const float*)Ap;
                float4 v0 = *(const float4*)(Af + (long)gr * K + k0 + kc * 8);
                float4 v1 = *(const float4*)(Af + (long)gr * K + k0 + kc * 8 + 4);
                v[0] = (short)f2bf(v0.x); v[1] = (short)f2bf(v0.y);
                v[2] = (short)f2bf(v0.z); v[3] = (short)f2bf(v0.w);
                v[4] = (short)f2bf(v1.x); v[5] = (short)f2bf(v1.y);
                v[6] = (short)f2bf(v1.z); v[7] = (short)f2bf(v1.w);
            } else {
                v = *(const bf16x8*)((const ushort*)Ap + (long)gr * K + k0 + kc * 8);
            }
            int di = (tid * 8) ^ ((r & 7) << 3);
            *(bf16x8*)&As[di] = v;
        }
        // ---- stage W tile ----
#pragma unroll
        for (int c = tid; c < N * 8; c += 256) {
            int r = c >> 3, kc = c & 7;
            bf16x8 v;
            if constexpr (WF32) {
                const float* Wf = (const float*)Wp;
                float4 v0 = *(const float4*)(Wf + (long)r * K + k0 + kc * 8);
                float4 v1 = *(const float4*)(Wf + (long)r * K + k0 + kc * 8 + 4);
                v[0] = (short)f2bf(v0.x); v[1] = (short)f2bf(v0.y);
                v[2] = (short)f2bf(v0.z); v[3] = (short)f2bf(v0.w);
                v[4] = (short)f2bf(v1.x); v[5] = (short)f2bf(v1.y);
                v[6] = (short)f2bf(v1.z); v[7] = (short)f2bf(v1.w);
            } else {
                v = *(const bf16x8*)((const ushort*)Wp + (long)r * K + k0 + kc * 8);
            }
            int di = (r * BK + kc * 8) ^ ((r & 7) << 3);
            *(bf16x8*)&Ws[di] = v;
        }
        __syncthreads();

#pragma unroll
        for (int ks = 0; ks < 2; ++ks) {
            const int kk = ks * 32 + l4 * 8;
            int rA = wr * 16 + l15;
            bf16x8 av = *(const bf16x8*)&As[(rA * BK + kk) ^ ((rA & 7) << 3)];
            bf16x8 bv[NC];
#pragma unroll
            for (int nc = 0; nc < NC; ++nc) {
                int rB = wc * (N / 2) + nc * 16 + l15;
                bv[nc] = *(const bf16x8*)&Ws[(rB * BK + kk) ^ ((rB & 7) << 3)];
            }
#pragma unroll
            for (int nc = 0; nc < NC; ++nc)
                acc[nc] = __builtin_amdgcn_mfma_f32_16x16x32_bf16(
                    av, bv[nc], acc[nc], 0, 0, 0);
        }
        __syncthreads();
    }

    // ---- epilogue ----
    short* Dt = (short*)smem;                 // FUSE_OUT: bf16 [32][128]
#pragma unroll
    for (int nc = 0; nc < NC; ++nc) {
        int gn = wc * (N / 2) + nc * 16 + l15;
#pragma unroll
        for (int j = 0; j < 4; ++j) {
            int gm = m0 + wr * 16 + l4 * 4 + j;
            float v = acc[nc][j];
            ushort bv16;
            if (EPI == 0) {
                v += bias[gn];
                v = fmaxf(v, 0.f);
                bv16 = f2bf(v);
                ((ushort*)Cout)[(long)gm * N + gn] = bv16;
            } else {
                v = fmaxf(v, 0.f);
                v = 0.8f * v + 0.1f * bf2f(pre[(long)gm * N + gn])
                             + 0.1f * bf2f(in0[(long)gm * N + gn]);
                bv16 = f2bf(v);
                ((ushort*)Cout)[(long)gm * N + gn] = bv16;
            }
            if constexpr (FUSE_OUT) {
                int row = wr * 16 + l4 * 4 + j;
                int e = row * 128 + gn;
                Dt[e ^ ((row & 7) << 3)] = (short)bv16;
            }
        }
    }

    if constexpr (FUSE_OUT) {
        // stage Wout [64][128] bf16 into Wt (swizzled): 1024 granules,
        // 16 granules per 128-elem row: r = c>>4, kc = c&15
        short* Wt = (short*)(smem + 8192);
        __syncthreads();   // Dt fully written; Ws/As dead
#pragma unroll
        for (int c = tid; c < 1024; c += 256) {
            int r = c >> 4, kc = c & 15;
            bf16x8 v = *(const bf16x8*)(Wtail + (long)r * HID + kc * 8);
            int di = (r * 128 + kc * 8) ^ ((r & 7) << 3);
            *(bf16x8*)&Wt[di] = v;
        }
        __syncthreads();

        // 32x64 = dst(32x128) @ Wout^T(64x128): 4 waves = 2 row x 2 col blocks
        const int wr2 = w >> 1, wc2 = w & 1;
        f32x4 acc2[2];
#pragma unroll
        for (int nc = 0; nc < 2; ++nc)
#pragma unroll
            for (int j = 0; j < 4; ++j) acc2[nc][j] = 0.f;

#pragma unroll
        for (int ksi = 0; ksi < 4; ++ksi) {
            const int kk = ksi * 32 + l4 * 8;
            int rA = wr2 * 16 + l15;
            bf16x8 av = *(const bf16x8*)&Dt[(rA * 128 + kk) ^ ((rA & 7) << 3)];
#pragma unroll
            for (int nc = 0; nc < 2; ++nc) {
                int rB = wc2 * 32 + nc * 16 + l15;
                bf16x8 bv = *(const bf16x8*)&Wt[(rB * 128 + kk) ^ ((rB & 7) << 3)];
                acc2[nc] = __builtin_amdgcn_mfma_f32_16x16x32_bf16(
                    av, bv, acc2[nc], 0, 0, 0);
            }
        }

#pragma unroll
        for (int nc = 0; nc < 2; ++nc) {
            int gn = wc2 * 32 + nc * 16 + l15;
#pragma unroll
            for (int j = 0; j < 4; ++j) {
                int gm = m0 + wr2 * 16 + l4 * 4 + j;
                float v = acc2[nc][j] + bias_tail[gn];
                out_tail[(long)gm * OUT_DIM + gn] = fmaxf(v, 0.f);
            }
        }
    }
}

// ---------------------------------------------------------------------------
// Gather with XCD-SEGREGATED h-halves: under the observed round-robin
// blockIdx->XCD dispatch, xcd = gb&7; XCDs 0-3 process h-half 0, XCDs 4-7
// h-half 1. Each XCD's concurrent feats working set = 2.56 MB < 4 MiB L2
// (vs 5.12 MB > L2 with the sequential-half mapping -> continuous thrash).
// Round-4's null for this mapping predates the MLP restructure (gather was
// latency-bound then; bandwidth-operating now). If XCD mapping differs,
// this is a pure permutation - correctness unaffected.
// Block = 16 nodes x 16 lanes; uint2 half-row loads (one 128-B line per
// 16-lane group); nontemporal paths loads + fout stores; weights in LDS.
// ---------------------------------------------------------------------------
__global__ __launch_bounds__(256, 4) void gather_bf16(
    const uint* __restrict__ feats_u,   // [NN][64]  (bf16x2 packed)
    const int* __restrict__ paths,      // [P][NN][L]
    const int* __restrict__ ptypes,     // [P]
    const float* __restrict__ pw,       // [2][L][HID] f32
    uint* __restrict__ fout_u)          // [NN][128] (bf16x2 packed)
{
    const int gb = (int)blockIdx.x;
    const int xcd = gb & 7;
    const int h_half = xcd >> 2;                  // XCD 0-3: half 0; 4-7: half 1
    const int ntile = (gb >> 3) * 4 + (xcd & 3);  // tile index within half
    if (ntile >= NN / 16) return;                 // block-uniform exit (pad)
    const int nbase = ntile * 16;

    const int tid = threadIdx.x;
    const int node = tid >> 4;          // 0..15
    const int l16 = tid & 15;           // channel quad within the h-half
    const int n = nbase + node;

    __shared__ int idx_l[16][N_TYPES][PATH_LEN][8];     // 8 KB
    __shared__ float wls[N_TYPES][PATH_LEN][64];        // 4 KB, pre-scaled

    uint tmask = 0;
#pragma unroll
    for (int p = 0; p < N_PATHS; ++p) tmask |= (uint)(ptypes[p] != 0) << p;
    const int cnt1 = __popc(tmask);
    const int cnt0 = N_PATHS - cnt1;
    const float inv0 = cnt0 ? 1.f / (float)cnt0 : 0.f;
    const float inv1 = cnt1 ? 1.f / (float)cnt1 : 0.f;

    // stage 16 nodes x 64 indices, sorted by (type, l, rank); nontemporal
#pragma unroll
    for (int j = 0; j < 4; ++j) {
        int li = tid * 4 + j;           // 0..1023
        int nd = li >> 6, k = li & 63, p = k >> 3, l = k & 7;
        int tp = (int)((tmask >> p) & 1u);
        uint below = tmask & ((1u << p) - 1u);
        int rank = tp ? __popc(below) : p - __popc(below);
        idx_l[nd][tp][l][rank] =
            __builtin_nontemporal_load(&paths[((long)p * NN + nbase + nd) * PATH_LEN + l]);
    }
    // stage pre-scaled weights for this h-half: 256 float4s, 1 per thread
    {
        int e = tid >> 7, l = (tid >> 4) & 7, c4 = tid & 15;
        float s = e ? inv1 : inv0;
        float4 t = *(const float4*)&pw[(e * PATH_LEN + l) * HID + h_half * 64 + c4 * 4];
        t.x *= s; t.y *= s; t.z *= s; t.w *= s;
        *(float4*)&wls[e][l][c4 * 4] = t;
    }
    __syncthreads();

    const long coff = h_half * 32 + l16 * 2;   // uint offset within a row
    float4 out[2];

#pragma unroll
    for (int e = 0; e < 2; ++e) {
        const int ce = e ? cnt1 : cnt0;
        float4 acc = {0.f, 0.f, 0.f, 0.f};
        if (ce == 4) {
            int4 r[PATH_LEN];
#pragma unroll
            for (int l = 0; l < PATH_LEN; ++l)
                r[l] = *(const int4*)&idx_l[node][e][l][0];
#pragma unroll
            for (int half = 0; half < 2; ++half) {
                uint2 g[4][4];
#pragma unroll
                for (int l = 0; l < 4; ++l) {
                    int4 rr = r[half * 4 + l];
                    g[l][0] = *(const uint2*)(feats_u + (long)rr.x * 64 + coff);
                    g[l][1] = *(const uint2*)(feats_u + (long)rr.y * 64 + coff);
                    g[l][2] = *(const uint2*)(feats_u + (long)rr.z * 64 + coff);
                    g[l][3] = *(const uint2*)(feats_u + (long)rr.w * 64 + coff);
                }
#pragma unroll
                for (int l = 0; l < 4; ++l) {
                    float sx = bf2f((ushort)(g[l][0].x & 0xffff)) + bf2f((ushort)(g[l][1].x & 0xffff))
                             + bf2f((ushort)(g[l][2].x & 0xffff)) + bf2f((ushort)(g[l][3].x & 0xffff));
                    float sy = bf2f((ushort)(g[l][0].x >> 16)) + bf2f((ushort)(g[l][1].x >> 16))
                             + bf2f((ushort)(g[l][2].x >> 16)) + bf2f((ushort)(g[l][3].x >> 16));
                    float sz = bf2f((ushort)(g[l][0].y & 0xffff)) + bf2f((ushort)(g[l][1].y & 0xffff))
                             + bf2f((ushort)(g[l][2].y & 0xffff)) + bf2f((ushort)(g[l][3].y & 0xffff));
                    float sw = bf2f((ushort)(g[l][0].y >> 16)) + bf2f((ushort)(g[l][1].y >> 16))
                             + bf2f((ushort)(g[l][2].y >> 16)) + bf2f((ushort)(g[l][3].y >> 16));
                    const float4 wv = *(const float4*)&wls[e][half * 4 + l][l16 * 4];
                    acc.x += sx * wv.x;
                    acc.y += sy * wv.y;
                    acc.z += sz * wv.z;
                    acc.w += sw * wv.w;
                }
            }
        } else {
#pragma unroll
            for (int l = 0; l < PATH_LEN; ++l) {
                float sx = 0.f, sy = 0.f, sz = 0.f, sw = 0.f;
                for (int q = 0; q < ce; ++q) {
                    int row = idx_l[node][e][l][q];
                    uint2 v = *(const uint2*)(feats_u + (long)row * 64 + coff);
                    sx += bf2f((ushort)(v.x & 0xffff));
                    sy += bf2f((ushort)(v.x >> 16));
                    sz += bf2f((ushort)(v.y & 0xffff));
                    sw += bf2f((ushort)(v.y >> 16));
                }
                const float4 wv = *(const float4*)&wls[e][l][l16 * 4];
                acc.x += sx * wv.x;
                acc.y += sy * wv.y;
                acc.z += sz * wv.z;
                acc.w += sw * wv.w;
            }
        }
        out[e] = acc;
    }

#pragma unroll
    for (int e = 0; e < 2; ++e) {
        uint2 o;
        o.x = (uint)f2bf(out[e].x) | ((uint)f2bf(out[e].y) << 16);
        o.y = (uint)f2bf(out[e].z) | ((uint)f2bf(out[e].w) << 16);
        unsigned long long packed = (unsigned long long)o.x
                                  | ((unsigned long long)o.y << 32);
        __builtin_nontemporal_store(packed,
            (unsigned long long*)(fout_u + (long)n * 128 + e * 64 + coff));
    }
}

// ---------------------------------------------------------------------------
extern "C" void kernel_launch(void* const* d_in, const int* in_sizes, int n_in,
                              void* d_out, int out_size, void* d_ws, size_t ws_size,
                              hipStream_t stream)
{
    const float* input_x      = (const float*)d_in[0];
    const int*   paths        = (const int*)d_in[1];
    const int*   path_types   = (const int*)d_in[2];
    const float* fc_in_w      = (const float*)d_in[3];
    const float* fc_in_b      = (const float*)d_in[4];
    const float* fc_out_w     = (const float*)d_in[5];
    const float* fc_out_b     = (const float*)d_in[6];
    const float* layer_fc_w   = (const float*)d_in[7];
    const float* path_weights = (const float*)d_in[8];
    float* out = (float*)d_out;

    char* p = (char*)d_ws;
    ushort* w_layer  = (ushort*)p; p += N_LAYERS * HID * N_TYPES * HID * 2; // 256 KB
    ushort* w_out    = (ushort*)p; p += OUT_DIM * HID * 2;                  // 16 KB
    ushort* in_feats = (ushort*)p; p += (long)NN * HID * 2;                 // 5.12 MB
    ushort* featsA   = (ushort*)p; p += (long)NN * HID * 2;
    ushort* featsB   = (ushort*)p; p += (long)NN * HID * 2;
    ushort* fout     = (ushort*)p; p += (long)NN * N_TYPES * HID * 2;       // 10.24 MB

    const int GG = NN / 32;                          // 625 (exact)
    const int GATHER_GRID = ((NN / 16 + 3) / 4) * 8; // 2504 (XCD-segregated)

    // fc_in (A,W fp32 convert-on-stage) + side-convert w_layer / w_out
    gemm_mfma<HID, IN_DIM, 0, true, true, true, false><<<GG, 256, 0, stream>>>(
        input_x, fc_in_w, fc_in_b, nullptr, nullptr, in_feats, NN,
        layer_fc_w, w_layer, fc_out_w, w_out,
        nullptr, nullptr, nullptr);

    const ushort* src = in_feats;
    ushort* dsts[N_LAYERS] = {featsA, featsB, featsA, featsB};
    for (int i = 0; i < N_LAYERS; ++i) {
        gather_bf16<<<GATHER_GRID, 256, 0, stream>>>(
            (const uint*)src, paths, path_types,
            path_weights + (long)i * N_TYPES * PATH_LEN * HID, (uint*)fout);
        if (i < N_LAYERS - 1) {
            gemm_mfma<HID, N_TYPES * HID, 1, false, false, false, false>
                <<<GG, 256, 0, stream>>>(
                fout, w_layer + (long)i * HID * N_TYPES * HID, nullptr,
                src, in_feats, dsts[i], NN,
                nullptr, nullptr, nullptr, nullptr, nullptr, nullptr, nullptr);
        } else {
            // layer 4 + fused fc_out tail
            gemm_mfma<HID, N_TYPES * HID, 1, false, false, false, true>
                <<<GG, 256, 0, stream>>>(
                fout, w_layer + (long)i * HID * N_TYPES * HID, nullptr,
                src, in_feats, dsts[i], NN,
                nullptr, nullptr, nullptr, nullptr,
                w_out, fc_out_b, out);
        }
        src = dsts[i];
    }
}